// Round 11
// baseline (1027.738 us; speedup 1.0000x reference)
//
#include <hip/hip_runtime.h>
#include <math.h>

#define BB 4
#define NN 2048
#define KK 20
#define EPSF 1e-5f
#define TR 4

__device__ __forceinline__ float leaky(float x){ return x > 0.f ? x : 0.2f*x; }
__device__ __forceinline__ float sigm(float x){ return 1.f/(1.f+expf(-x)); }

// 64-lane max reduce via DPP (row_shr chain + row_bcast), result wave-uniform.
__device__ __forceinline__ unsigned wave_umax_dpp(unsigned x){
  unsigned t;
  t = (unsigned)__builtin_amdgcn_update_dpp(0, (int)x, 0x111, 0xf, 0xf, true); x = x > t ? x : t; // row_shr:1
  t = (unsigned)__builtin_amdgcn_update_dpp(0, (int)x, 0x112, 0xf, 0xf, true); x = x > t ? x : t; // row_shr:2
  t = (unsigned)__builtin_amdgcn_update_dpp(0, (int)x, 0x114, 0xf, 0xf, true); x = x > t ? x : t; // row_shr:4
  t = (unsigned)__builtin_amdgcn_update_dpp(0, (int)x, 0x118, 0xf, 0xf, true); x = x > t ? x : t; // row_shr:8
  t = (unsigned)__builtin_amdgcn_update_dpp(0, (int)x, 0x142, 0xf, 0xf, true); x = x > t ? x : t; // row_bcast:15
  t = (unsigned)__builtin_amdgcn_update_dpp(0, (int)x, 0x143, 0xf, 0xf, true); x = x > t ? x : t; // row_bcast:31
  return (unsigned)__builtin_amdgcn_readlane((int)x, 63);
}

// --- KNN: top-20 of pd[n,m] = 2*dot - xx[n] - xx[m], ties -> smaller index ---
// R4 structure (TR=4 rows/block, 1 row/wave, vectorized dot, DPP extraction),
// with xx computed INLINE (same c-ascending fmaf chain -> bit-identical pd).
__global__ __launch_bounds__(256) void k_knn(const float* __restrict__ X, long bstride, int C,
                      int* __restrict__ idx){
  __shared__ unsigned int pdrow[TR][NN];   // exactly 32 KB
  int rowsPerB = NN/TR;
  int b = blockIdx.x / rowsPerB;
  int r0 = (blockIdx.x % rowsPerB) * TR;
  const float* xb = X + (long)b*bstride;
  int tid = threadIdx.x;
  int m0 = tid << 3;                        // 8 consecutive m per thread

  float acc[4][8];
  float cxx[4] = {0.f,0.f,0.f,0.f};         // xx of the 4 rows
  float vxx[8] = {0.f,0.f,0.f,0.f,0.f,0.f,0.f,0.f}; // xx of the 8 m's
  #pragma unroll
  for (int r = 0; r < 4; ++r)
    #pragma unroll
    for (int j = 0; j < 8; ++j) acc[r][j] = 0.f;
  for (int c = 0; c < C; ++c){
    const float* xcp = xb + (long)c*NN;
    float4 ctr = *(const float4*)(xcp + r0);
    float4 va = *(const float4*)(xcp + m0);
    float4 vb = *(const float4*)(xcp + m0 + 4);
    float v[8] = {va.x,va.y,va.z,va.w,vb.x,vb.y,vb.z,vb.w};
    #pragma unroll
    for (int j = 0; j < 8; ++j){
      acc[0][j] = fmaf(ctr.x, v[j], acc[0][j]);
      acc[1][j] = fmaf(ctr.y, v[j], acc[1][j]);
      acc[2][j] = fmaf(ctr.z, v[j], acc[2][j]);
      acc[3][j] = fmaf(ctr.w, v[j], acc[3][j]);
    }
    cxx[0] = fmaf(ctr.x, ctr.x, cxx[0]);
    cxx[1] = fmaf(ctr.y, ctr.y, cxx[1]);
    cxx[2] = fmaf(ctr.z, ctr.z, cxx[2]);
    cxx[3] = fmaf(ctr.w, ctr.w, cxx[3]);
    #pragma unroll
    for (int j = 0; j < 8; ++j) vxx[j] = fmaf(v[j], v[j], vxx[j]);
  }
  #pragma unroll
  for (int r = 0; r < 4; ++r){
    unsigned u[8];
    #pragma unroll
    for (int j = 0; j < 8; ++j){
      float pd = 2.f*acc[r][j] - cxx[r] - vxx[j];
      unsigned uu = __float_as_uint(pd);
      uu ^= (uu & 0x80000000u) ? 0xFFFFFFFFu : 0x80000000u;  // order-preserving
      u[j] = uu;
    }
    *(uint4*)&pdrow[r][m0]     = make_uint4(u[0],u[1],u[2],u[3]);
    *(uint4*)&pdrow[r][m0 + 4] = make_uint4(u[4],u[5],u[6],u[7]);
  }
  __syncthreads();

  int wave = tid >> 6, lane = tid & 63;
  int r = wave;  // one wave per row
  unsigned long long k1 = 0ull, k2 = 0ull;
  #pragma unroll
  for (int j = 0; j < 32; ++j){
    int m = lane + (j<<6);
    unsigned long long key = ((unsigned long long)pdrow[r][m] << 11) | (unsigned)(2047 - m);
    if (key > k1){ k2 = k1; k1 = key; }
    else if (key > k2){ k2 = key; }
  }
  unsigned removed = 0u;
  int* orow = idx + ((long)b*NN + r0 + r)*KK;
  for (int sel = 0; sel < KK; ++sel){
    unsigned p = (unsigned)(k1 >> 11);      // pd32; 0 iff lane exhausted
    unsigned g = wave_umax_dpp(p);
    unsigned long long tied = __ballot(p == g);
    if (__builtin_popcountll(tied) > 1){
      // rare: exact pd-bit tie across lanes -> pick smallest m (max of 2047-m)
      unsigned low = (p == g) ? (unsigned)(k1 & 2047ull) : 0u;
      unsigned gl = wave_umax_dpp(low);
      tied = __ballot((p == g) && (low == gl));
    }
    int owner = (int)__builtin_ctzll(tied);
    if (lane == owner){
      int gm = 2047 - (int)(k1 & 2047ull);
      orow[sel] = gm;
      removed |= 1u << (gm >> 6);
      k1 = k2; k2 = 0ull;
      if (k1 == 0ull && sel < KK-1){
        // lane exhausted its top-2: rescan remaining candidates from LDS
        #pragma unroll
        for (int j = 0; j < 32; ++j){
          if (removed & (1u << j)) continue;
          int m = lane + (j<<6);
          unsigned long long key = ((unsigned long long)pdrow[r][m] << 11) | (unsigned)(2047 - m);
          if (key > k1){ k2 = k1; k1 = key; }
          else if (key > k2){ k2 = key; }
        }
      }
    }
  }
}

// --- naive projections (used only for block 0, C=3) ---
__global__ void k_proj(const float* __restrict__ X, long bstride, int C, int Cout,
                       const float* __restrict__ W, const float* __restrict__ bn,
                       float* __restrict__ Pg, float* __restrict__ PgT,
                       float* __restrict__ Pc, float* __restrict__ PcT){
  int nb = NN/256;
  int t = blockIdx.x;
  int nchunk = t % nb; t /= nb;
  int o = t % Cout; int b = t / Cout;
  int m = nchunk*256 + threadIdx.x;
  const float* xb = X + (long)b*bstride;
  float a1 = 0.f, a2 = 0.f;
  for (int c = 0; c < C; ++c){
    float v  = xb[c*NN + m];
    float wl = W[o*2*C + c], wr = W[o*2*C + C + c];
    a1 += wl*v; a2 += (wr - wl)*v;
  }
  float gg = bn[o], bb = bn[Cout+o], mn = bn[2*Cout+o], vv = bn[3*Cout+o];
  float scale = gg * rsqrtf(vv + EPSF);
  float bias  = bb - mn*scale;
  float pg = scale*a1;
  float pc = scale*a2 + bias;
  Pg [((long)b*Cout + o)*NN + m] = pg;
  PgT[((long)b*NN + m)*Cout + o] = pg;
  Pc [((long)b*Cout + o)*NN + m] = pc;
  PcT[((long)b*NN + m)*Cout + o] = pc;
}

// --- tiled projections: 64(o) x 128(n) per block, c-chunks of 32 in LDS ---
__global__ __launch_bounds__(256) void k_proj_t(const float* __restrict__ X, long bstride, int C, int Cout,
                         const float* __restrict__ W, const float* __restrict__ bn,
                         float* __restrict__ Pg, float* __restrict__ PgT,
                         float* __restrict__ Pc, float* __restrict__ PcT){
  __shared__ float xs[32][128];    // 16 KB  X chunk
  __shared__ float wls[64][33];    // 8.4 KB W_left chunk (pad 33)
  __shared__ float wds[64][33];    // 8.4 KB (W_right - W_left) chunk
  int t = blockIdx.x;
  int nb = t & 15; t >>= 4;        // NN/128 = 16 n-tiles
  int nob = Cout >> 6;
  int ob = t % nob; int b = t / nob;
  int n0 = nb << 7, o0 = ob << 6;
  int tid = threadIdx.x;
  int tx = tid & 15, ty = tid >> 4;   // tx: 16 n-slots (x4), ty: 16 o-quads
  const float* xb = X + (long)b*bstride + n0;

  float ag[4][8], ac[4][8];
  #pragma unroll
  for (int i = 0; i < 4; ++i)
    #pragma unroll
    for (int j = 0; j < 8; ++j){ ag[i][j] = 0.f; ac[i][j] = 0.f; }

  for (int cc = 0; cc < C; cc += 32){
    {
      int col4 = tid & 31;   // col = col4*4
      int ci0 = tid >> 5;    // 0..7
      #pragma unroll
      for (int q = 0; q < 4; ++q){
        int ci = ci0 + (q << 3);
        float4 v = *(const float4*)(xb + (long)(cc + ci)*NN + (col4 << 2));
        *(float4*)&xs[ci][col4 << 2] = v;
      }
    }
    {
      int ci4 = tid & 7;     // c = ci4*4
      int oi0 = tid >> 3;    // 0..31
      #pragma unroll
      for (int q = 0; q < 2; ++q){
        int oi = oi0 + (q << 5);
        const float* wrow = W + (long)(o0 + oi)*2*C + cc + (ci4 << 2);
        float4 wl = *(const float4*)(wrow);
        float4 wr = *(const float4*)(wrow + C);
        wls[oi][(ci4 << 2) + 0] = wl.x;
        wls[oi][(ci4 << 2) + 1] = wl.y;
        wls[oi][(ci4 << 2) + 2] = wl.z;
        wls[oi][(ci4 << 2) + 3] = wl.w;
        wds[oi][(ci4 << 2) + 0] = wr.x - wl.x;
        wds[oi][(ci4 << 2) + 1] = wr.y - wl.y;
        wds[oi][(ci4 << 2) + 2] = wr.z - wl.z;
        wds[oi][(ci4 << 2) + 3] = wr.w - wl.w;
      }
    }
    __syncthreads();
    #pragma unroll 8
    for (int ci = 0; ci < 32; ++ci){
      float4 xa  = *(const float4*)&xs[ci][tx << 2];
      float4 xc2 = *(const float4*)&xs[ci][64 + (tx << 2)];
      #pragma unroll
      for (int oo = 0; oo < 4; ++oo){
        float wl = wls[(ty << 2) + oo][ci];
        float wd = wds[(ty << 2) + oo][ci];
        ag[oo][0] = fmaf(wl, xa.x, ag[oo][0]); ag[oo][1] = fmaf(wl, xa.y, ag[oo][1]);
        ag[oo][2] = fmaf(wl, xa.z, ag[oo][2]); ag[oo][3] = fmaf(wl, xa.w, ag[oo][3]);
        ag[oo][4] = fmaf(wl, xc2.x, ag[oo][4]); ag[oo][5] = fmaf(wl, xc2.y, ag[oo][5]);
        ag[oo][6] = fmaf(wl, xc2.z, ag[oo][6]); ag[oo][7] = fmaf(wl, xc2.w, ag[oo][7]);
        ac[oo][0] = fmaf(wd, xa.x, ac[oo][0]); ac[oo][1] = fmaf(wd, xa.y, ac[oo][1]);
        ac[oo][2] = fmaf(wd, xa.z, ac[oo][2]); ac[oo][3] = fmaf(wd, xa.w, ac[oo][3]);
        ac[oo][4] = fmaf(wd, xc2.x, ac[oo][4]); ac[oo][5] = fmaf(wd, xc2.y, ac[oo][5]);
        ac[oo][6] = fmaf(wd, xc2.z, ac[oo][6]); ac[oo][7] = fmaf(wd, xc2.w, ac[oo][7]);
      }
    }
    __syncthreads();
  }

  float scl[4], bia[4];
  #pragma unroll
  for (int oo = 0; oo < 4; ++oo){
    int o = o0 + (ty << 2) + oo;
    scl[oo] = bn[o] * rsqrtf(bn[3*Cout + o] + EPSF);
    bia[oo] = bn[Cout + o] - bn[2*Cout + o]*scl[oo];
  }
  #pragma unroll
  for (int oo = 0; oo < 4; ++oo){
    long rb = ((long)b*Cout + o0 + (ty << 2) + oo)*NN + n0;
    float4 g0 = {scl[oo]*ag[oo][0], scl[oo]*ag[oo][1], scl[oo]*ag[oo][2], scl[oo]*ag[oo][3]};
    float4 g1 = {scl[oo]*ag[oo][4], scl[oo]*ag[oo][5], scl[oo]*ag[oo][6], scl[oo]*ag[oo][7]};
    float4 c0 = {fmaf(scl[oo], ac[oo][0], bia[oo]), fmaf(scl[oo], ac[oo][1], bia[oo]),
                 fmaf(scl[oo], ac[oo][2], bia[oo]), fmaf(scl[oo], ac[oo][3], bia[oo])};
    float4 c1 = {fmaf(scl[oo], ac[oo][4], bia[oo]), fmaf(scl[oo], ac[oo][5], bia[oo]),
                 fmaf(scl[oo], ac[oo][6], bia[oo]), fmaf(scl[oo], ac[oo][7], bia[oo])};
    *(float4*)(Pg + rb + (tx << 2))      = g0;
    *(float4*)(Pg + rb + 64 + (tx << 2)) = g1;
    *(float4*)(Pc + rb + (tx << 2))      = c0;
    *(float4*)(Pc + rb + 64 + (tx << 2)) = c1;
  }
  #pragma unroll
  for (int j = 0; j < 8; ++j){
    int n = n0 + ((j < 4) ? (tx << 2) + j : 64 + (tx << 2) + (j - 4));
    long rb = ((long)b*NN + n)*Cout + o0 + (ty << 2);
    float4 tg = {scl[0]*ag[0][j], scl[1]*ag[1][j], scl[2]*ag[2][j], scl[3]*ag[3][j]};
    float4 tc = {fmaf(scl[0], ac[0][j], bia[0]), fmaf(scl[1], ac[1][j], bia[1]),
                 fmaf(scl[2], ac[2][j], bia[2]), fmaf(scl[3], ac[3][j], bia[3])};
    *(float4*)(PgT + rb) = tg;
    *(float4*)(PcT + rb) = tc;
  }
}

// --- channel mean/max over (n,k) of leaky(Pg[idx]+Pc[n]) ---
__global__ void k_cstats(const float* __restrict__ Pg, const float* __restrict__ Pc,
                         const int* __restrict__ idx, int Cout,
                         float* __restrict__ cmean, float* __restrict__ cmax){
  int b = blockIdx.x / Cout, o = blockIdx.x % Cout;
  const float* pg = Pg + ((long)b*Cout + o)*NN;
  const float* pc = Pc + ((long)b*Cout + o)*NN;
  const int* id = idx + (long)b*NN*KK;
  int tid = threadIdx.x;
  float s = 0.f, mx = -INFINITY;
  for (int i = tid; i < NN*KK; i += 256){
    int n = i / KK;
    int iv = id[i];
    float v = leaky(pg[iv] + pc[n]);
    s += v; mx = fmaxf(mx, v);
  }
  __shared__ float ss[256], sm[256];
  ss[tid] = s; sm[tid] = mx; __syncthreads();
  for (int st = 128; st; st >>= 1){
    if (tid < st){ ss[tid] += ss[tid+st]; sm[tid] = fmaxf(sm[tid], sm[tid+st]); }
    __syncthreads();
  }
  if (tid == 0){ cmean[blockIdx.x] = ss[0]/(float)(NN*KK); cmax[blockIdx.x] = sm[0]; }
}

// --- channel attention MLP ---
__global__ void k_catt(const float* __restrict__ cmean, const float* __restrict__ cmax,
                       const float* __restrict__ fc1, const float* __restrict__ fc2,
                       int Cout, int r, float* __restrict__ ca){
  int b = blockIdx.x, tid = threadIdx.x;
  __shared__ float h1m[32], h1x[32];
  __shared__ float mv[256], xv[256];
  if (tid < Cout){ mv[tid] = cmean[b*Cout+tid]; xv[tid] = cmax[b*Cout+tid]; }
  __syncthreads();
  if (tid < r){
    float am = 0.f, ax = 0.f;
    for (int c = 0; c < Cout; ++c){ float w = fc1[tid*Cout+c]; am += w*mv[c]; ax += w*xv[c]; }
    h1m[tid] = fmaxf(am, 0.f); h1x[tid] = fmaxf(ax, 0.f);
  }
  __syncthreads();
  if (tid < Cout){
    float a = 0.f;
    for (int j = 0; j < r; ++j) a += fc2[tid*r+j]*(h1m[j] + h1x[j]);
    ca[b*Cout+tid] = sigm(a);
  }
}

// --- spatial mean/max over channels of act*ca (float4 rows of PgT/PcT) ---
__global__ void k_sstats(const float* __restrict__ PgT, const float* __restrict__ PcT,
                         const int* __restrict__ idx, const float* __restrict__ ca,
                         int Cout, float* __restrict__ s){
  long i = (long)blockIdx.x*256 + threadIdx.x; // over BB*NN*KK
  int kk = (int)(i % KK); long t = i / KK; int n = (int)(t % NN); int b = (int)(t / NN);
  int iv = idx[((long)b*NN + n)*KK + kk];
  const float4* pg4 = (const float4*)(PgT + ((long)b*NN + iv)*Cout);
  const float4* pc4 = (const float4*)(PcT + ((long)b*NN + n)*Cout);
  const float4* ca4 = (const float4*)(ca + b*Cout);
  float sum = 0.f, mx = -INFINITY;
  int q = Cout >> 2;
  for (int o = 0; o < q; ++o){
    float4 a = pg4[o], c = pc4[o], w = ca4[o];
    float v0 = leaky(a.x + c.x) * w.x;
    float v1 = leaky(a.y + c.y) * w.y;
    float v2 = leaky(a.z + c.z) * w.z;
    float v3 = leaky(a.w + c.w) * w.w;
    sum += v0; mx = fmaxf(mx, v0);
    sum += v1; mx = fmaxf(mx, v1);
    sum += v2; mx = fmaxf(mx, v2);
    sum += v3; mx = fmaxf(mx, v3);
  }
  s[((long)b*2*NN + n)*KK + kk]      = sum/(float)Cout;
  s[((long)b*2*NN + NN + n)*KK + kk] = mx;
}

// --- 5x5 spatial conv (pad 2) + sigmoid ---
__global__ void k_sconv(const float* __restrict__ s, const float* __restrict__ sw,
                        float* __restrict__ sa){
  long i = (long)blockIdx.x*256 + threadIdx.x; // over BB*NN*KK
  int kk = (int)(i % KK); long t = i / KK; int n = (int)(t % NN); int b = (int)(t / NN);
  float acc = 0.f;
  for (int ci = 0; ci < 2; ++ci)
    for (int dy = 0; dy < 5; ++dy){
      int nn = n + dy - 2; if (nn < 0 || nn >= NN) continue;
      for (int dx = 0; dx < 5; ++dx){
        int kx = kk + dx - 2; if (kx < 0 || kx >= KK) continue;
        acc += sw[ci*25 + dy*5 + dx] * s[((long)b*2*NN + ci*NN + nn)*KK + kx];
      }
    }
  sa[i] = sigm(acc);
}

// --- final: max over k of act*ca*sa -> xc ---
__global__ void k_final(const float* __restrict__ Pg, const float* __restrict__ Pc,
                        const int* __restrict__ idx, const float* __restrict__ ca,
                        const float* __restrict__ sa, int Cout, int outoff,
                        float* __restrict__ xc){
  long i = (long)blockIdx.x*256 + threadIdx.x; // over BB*Cout*NN, n fastest
  int n = (int)(i % NN); long t = i / NN; int o = (int)(t % Cout); int b = (int)(t / Cout);
  const float* pg = Pg + ((long)b*Cout + o)*NN;
  float pcv = Pc[((long)b*Cout + o)*NN + n];
  float cav = ca[b*Cout + o];
  const int* id   = idx + ((long)b*NN + n)*KK;
  const float* sb = sa  + ((long)b*NN + n)*KK;
  float mx = -INFINITY;
  for (int kk = 0; kk < KK; ++kk){
    float v = leaky(pg[id[kk]] + pcv) * cav * sb[kk];
    mx = fmaxf(mx, v);
  }
  xc[((long)b*512 + outoff + o)*NN + n] = mx;
}

// --- gemm5 tiled: 64(o) x 128(n) per block, fused bn5+leaky+partial pool.
//     Register double-buffered staging; __launch_bounds__(256,4) raises the
//     VGPR budget to 128 so the prefetch stays in registers (R10 spilled at
//     the default 64-VGPR target: WRITE_SIZE 512KB -> 115MB scratch). ---
__global__ __launch_bounds__(256, 4) void k_gemm5(const float* __restrict__ xc, const float* __restrict__ W5,
                        const float* __restrict__ bn5, float* __restrict__ gpart){
  __shared__ float xs[32][128];    // 16 KB
  __shared__ float wsd[64][33];    // 8.4 KB, pad 33 -> conflict-free ty reads
  int t = blockIdx.x;
  int nb = t & 15; t >>= 4;
  int ob = t & 15; int b = t >> 4;
  int n0 = nb << 7, o0 = ob << 6;
  int tid = threadIdx.x;
  int tx = tid & 15, ty = tid >> 4;   // ty: 16 o-quads, tx: 16 n-slots
  const float* xb = xc + (long)b*512*NN + n0;

  int col4 = tid & 31;   // x-stage: col = col4*4
  int ci0  = tid >> 5;   // 0..7
  int wci4 = tid & 7;    // w-stage: c = wci4*4
  int woi0 = tid >> 3;   // 0..31

  float acc[4][8];
  #pragma unroll
  for (int i = 0; i < 4; ++i)
    #pragma unroll
    for (int j = 0; j < 8; ++j) acc[i][j] = 0.f;

  // preload chunk 0 into registers
  float4 xv[4], wv[2];
  #pragma unroll
  for (int q = 0; q < 4; ++q)
    xv[q] = *(const float4*)(xb + (long)(ci0 + (q << 3))*NN + (col4 << 2));
  #pragma unroll
  for (int q = 0; q < 2; ++q)
    wv[q] = *(const float4*)(W5 + (long)(o0 + woi0 + (q << 5))*512 + (wci4 << 2));

  for (int cc = 0; cc < 16; ++cc){
    // store staged registers to LDS
    #pragma unroll
    for (int q = 0; q < 4; ++q)
      *(float4*)&xs[ci0 + (q << 3)][col4 << 2] = xv[q];
    #pragma unroll
    for (int q = 0; q < 2; ++q){
      int oi = woi0 + (q << 5);
      wsd[oi][(wci4 << 2) + 0] = wv[q].x;
      wsd[oi][(wci4 << 2) + 1] = wv[q].y;
      wsd[oi][(wci4 << 2) + 2] = wv[q].z;
      wsd[oi][(wci4 << 2) + 3] = wv[q].w;
    }
    __syncthreads();
    // prefetch chunk cc+1 (wave-uniform guard); overlaps the FMA loop below
    if (cc < 15){
      #pragma unroll
      for (int q = 0; q < 4; ++q)
        xv[q] = *(const float4*)(xb + (long)((cc+1)*32 + ci0 + (q << 3))*NN + (col4 << 2));
      #pragma unroll
      for (int q = 0; q < 2; ++q)
        wv[q] = *(const float4*)(W5 + (long)(o0 + woi0 + (q << 5))*512 + (cc+1)*32 + (wci4 << 2));
    }
    #pragma unroll 8
    for (int ci = 0; ci < 32; ++ci){
      float4 xa = *(const float4*)&xs[ci][tx << 2];
      float4 xc2 = *(const float4*)&xs[ci][64 + (tx << 2)];
      float w0 = wsd[(ty << 2) + 0][ci];
      float w1 = wsd[(ty << 2) + 1][ci];
      float w2 = wsd[(ty << 2) + 2][ci];
      float w3 = wsd[(ty << 2) + 3][ci];
      acc[0][0] = fmaf(w0, xa.x, acc[0][0]); acc[0][1] = fmaf(w0, xa.y, acc[0][1]);
      acc[0][2] = fmaf(w0, xa.z, acc[0][2]); acc[0][3] = fmaf(w0, xa.w, acc[0][3]);
      acc[0][4] = fmaf(w0, xc2.x, acc[0][4]); acc[0][5] = fmaf(w0, xc2.y, acc[0][5]);
      acc[0][6] = fmaf(w0, xc2.z, acc[0][6]); acc[0][7] = fmaf(w0, xc2.w, acc[0][7]);
      acc[1][0] = fmaf(w1, xa.x, acc[1][0]); acc[1][1] = fmaf(w1, xa.y, acc[1][1]);
      acc[1][2] = fmaf(w1, xa.z, acc[1][2]); acc[1][3] = fmaf(w1, xa.w, acc[1][3]);
      acc[1][4] = fmaf(w1, xc2.x, acc[1][4]); acc[1][5] = fmaf(w1, xc2.y, acc[1][5]);
      acc[1][6] = fmaf(w1, xc2.z, acc[1][6]); acc[1][7] = fmaf(w1, xc2.w, acc[1][7]);
      acc[2][0] = fmaf(w2, xa.x, acc[2][0]); acc[2][1] = fmaf(w2, xa.y, acc[2][1]);
      acc[2][2] = fmaf(w2, xa.z, acc[2][2]); acc[2][3] = fmaf(w2, xa.w, acc[2][3]);
      acc[2][4] = fmaf(w2, xc2.x, acc[2][4]); acc[2][5] = fmaf(w2, xc2.y, acc[2][5]);
      acc[2][6] = fmaf(w2, xc2.z, acc[2][6]); acc[2][7] = fmaf(w2, xc2.w, acc[2][7]);
      acc[3][0] = fmaf(w3, xa.x, acc[3][0]); acc[3][1] = fmaf(w3, xa.y, acc[3][1]);
      acc[3][2] = fmaf(w3, xa.z, acc[3][2]); acc[3][3] = fmaf(w3, xa.w, acc[3][3]);
      acc[3][4] = fmaf(w3, xc2.x, acc[3][4]); acc[3][5] = fmaf(w3, xc2.y, acc[3][5]);
      acc[3][6] = fmaf(w3, xc2.z, acc[3][6]); acc[3][7] = fmaf(w3, xc2.w, acc[3][7]);
    }
    __syncthreads();
  }

  // bn5 + leaky + pool over this thread's 8 n
  float psum[4], pmax[4];
  #pragma unroll
  for (int oo = 0; oo < 4; ++oo){
    int o = o0 + (ty << 2) + oo;
    float scale = bn5[o] * rsqrtf(bn5[3072 + o] + EPSF);
    float bias  = bn5[1024 + o] - bn5[2048 + o] * scale;
    float s = 0.f, mx = -INFINITY;
    #pragma unroll
    for (int j = 0; j < 8; ++j){
      float v = leaky(fmaf(scale, acc[oo][j], bias));
      s += v; mx = fmaxf(mx, v);
    }
    psum[oo] = s; pmax[oo] = mx;
  }
  __syncthreads();
  float* ps = &xs[0][0];          // [64][17]
  float* pm = ps + 64*17;         // [64][17]  (2176 floats < 4096)
  #pragma unroll
  for (int oo = 0; oo < 4; ++oo){
    int o = (ty << 2) + oo;
    ps[o*17 + tx] = psum[oo];
    pm[o*17 + tx] = pmax[oo];
  }
  __syncthreads();
  if (tid < 64){
    float s = 0.f, mx = -INFINITY;
    #pragma unroll
    for (int j = 0; j < 16; ++j){
      s += ps[tid*17 + j];
      mx = fmaxf(mx, pm[tid*17 + j]);
    }
    long base = ((long)(b*16 + nb))*1024 + o0 + tid;
    gpart[base] = s;
    gpart[65536 + base] = mx;
  }
}

// --- finish pool: g = [max, sum/2048] ---
__global__ void k_pool2(const float* __restrict__ gpart, float* __restrict__ g){
  int i = blockIdx.x*256 + threadIdx.x;  // over 4096
  int b = i >> 10, o = i & 1023;
  float s = 0.f, mx = -INFINITY;
  for (int nb = 0; nb < 16; ++nb){
    s += gpart[((long)(b*16 + nb))*1024 + o];
    mx = fmaxf(mx, gpart[65536 + ((long)(b*16 + nb))*1024 + o]);
  }
  g[b*2048 + o] = mx;
  g[b*2048 + 1024 + o] = s * (1.f/2048.f);
}

// --- dense: out = [leaky(bn(.))] (w @ in [+ bias]) ---
__global__ void k_dense(const float* __restrict__ in, const float* __restrict__ w,
                        const float* __restrict__ bias, const float* __restrict__ bnp,
                        int Cin, int Cout, float* __restrict__ out){
  int b = blockIdx.x / Cout, j = blockIdx.x % Cout;
  int tid = threadIdx.x;
  float a = 0.f;
  for (int c = tid; c < Cin; c += 256) a += w[(long)j*Cin + c]*in[(long)b*Cin + c];
  __shared__ float ss[256];
  ss[tid] = a; __syncthreads();
  for (int st = 128; st; st >>= 1){
    if (tid < st) ss[tid] += ss[tid+st];
    __syncthreads();
  }
  if (tid == 0){
    float v = ss[0];
    if (bias) v += bias[j];
    if (bnp){
      float scale = bnp[j]*rsqrtf(bnp[3*Cout+j] + EPSF);
      float bb    = bnp[Cout+j] - bnp[2*Cout+j]*scale;
      v = leaky(v*scale + bb);
    }
    out[b*Cout + j] = v;
  }
}

extern "C" void kernel_launch(void* const* d_in, const int* in_sizes, int n_in,
                              void* d_out, int out_size, void* d_ws, size_t ws_size,
                              hipStream_t stream){
  (void)in_sizes; (void)n_in; (void)out_size;
  const float* x  = (const float*)d_in[0];
  const float* Wb[4]  = {(const float*)d_in[1], (const float*)d_in[2], (const float*)d_in[3], (const float*)d_in[4]};
  const float* W5     = (const float*)d_in[5];
  const float* bnb[4] = {(const float*)d_in[6], (const float*)d_in[7], (const float*)d_in[8], (const float*)d_in[9]};
  const float* bn5    = (const float*)d_in[10];
  const float* bn6    = (const float*)d_in[11];
  const float* bn7    = (const float*)d_in[12];
  const float* fc1b[4] = {(const float*)d_in[13], (const float*)d_in[16], (const float*)d_in[19], (const float*)d_in[22]};
  const float* fc2b[4] = {(const float*)d_in[14], (const float*)d_in[17], (const float*)d_in[20], (const float*)d_in[23]};
  const float* swb[4]  = {(const float*)d_in[15], (const float*)d_in[18], (const float*)d_in[21], (const float*)d_in[24]};
  const float* lin1_w = (const float*)d_in[25];
  const float* lin2_w = (const float*)d_in[26];
  const float* lin2_b = (const float*)d_in[27];
  const float* lin3_w = (const float*)d_in[28];
  const float* lin3_b = (const float*)d_in[29];

  // workspace layout (floats)
  float* ws = (float*)d_ws;
  float* xc = ws;                                  // 4*512*2048 = 4,194,304
  float* tb = ws + (size_t)BB*512*NN;
  // (first 8192 floats of tb reserved — layout kept identical to prior rounds)
  int*   idx  = (int*)(tb + 8192);                 // 163,840 ints
  float* Pg   = tb + 8192 + 163840;                // 2,097,152 each (max Cout=256)
  float* PgT  = Pg  + 2097152;
  float* Pc   = PgT + 2097152;
  float* PcT  = Pc  + 2097152;
  float* cmean = PcT + 2097152;                    // 1024
  float* cmax  = cmean + 1024;
  float* ca    = cmax + 1024;
  float* s     = ca + 1024;                        // 327,680
  float* sa    = s + 327680;                       // 163,840
  // post-block region (reuses tb)
  float* gpart = tb;                               // 131,072 (sums + maxes)
  float* g  = tb + 131072;                         // 8,192
  float* t1 = g + 8192;                            // 2,048
  float* t2 = t1 + 2048;                           // 1,024
  size_t needed = ((size_t)BB*512*NN + 9055232) * 4;
  if (ws_size < needed) return;  // workspace too small: fail visibly

  const int Cin [4] = {3, 64, 64, 128};
  const int Cout[4] = {64, 64, 128, 256};
  const int inoff[4]  = {0, 0, 64, 128};
  const int outoff[4] = {0, 64, 128, 256};

  for (int blk = 0; blk < 4; ++blk){
    const float* Xp; long bstr;
    if (blk == 0){ Xp = x; bstr = 3l*NN; }
    else { Xp = xc + (long)inoff[blk]*NN; bstr = 512l*NN; }
    int C = Cin[blk], Co = Cout[blk];
    hipLaunchKernelGGL(k_knn,   dim3(BB*NN/TR),  dim3(256), 0, stream, Xp, bstr, C, idx);
    if (blk == 0){
      hipLaunchKernelGGL(k_proj,  dim3(BB*Co*(NN/256)), dim3(256), 0, stream, Xp, bstr, C, Co, Wb[blk], bnb[blk], Pg, PgT, Pc, PcT);
    } else {
      hipLaunchKernelGGL(k_proj_t, dim3(BB*(Co>>6)*16), dim3(256), 0, stream, Xp, bstr, C, Co, Wb[blk], bnb[blk], Pg, PgT, Pc, PcT);
    }
    hipLaunchKernelGGL(k_cstats, dim3(BB*Co), dim3(256), 0, stream, Pg, Pc, idx, Co, cmean, cmax);
    hipLaunchKernelGGL(k_catt,  dim3(BB), dim3(256), 0, stream, cmean, cmax, fc1b[blk], fc2b[blk], Co, Co/8, ca);
    hipLaunchKernelGGL(k_sstats, dim3(BB*NN*KK/256), dim3(256), 0, stream, PgT, PcT, idx, ca, Co, s);
    hipLaunchKernelGGL(k_sconv, dim3(BB*NN*KK/256), dim3(256), 0, stream, s, swb[blk], sa);
    hipLaunchKernelGGL(k_final, dim3(BB*Co*NN/256), dim3(256), 0, stream, Pg, Pc, idx, ca, sa, Co, outoff[blk], xc);
  }
  hipLaunchKernelGGL(k_gemm5, dim3(BB*16*16), dim3(256), 0, stream, xc, W5, bn5, gpart);
  hipLaunchKernelGGL(k_pool2, dim3(16), dim3(256), 0, stream, gpart, g);
  hipLaunchKernelGGL(k_dense, dim3(BB*512), dim3(256), 0, stream, g,  lin1_w, (const float*)nullptr, bn6, 2048, 512, t1);
  hipLaunchKernelGGL(k_dense, dim3(BB*256), dim3(256), 0, stream, t1, lin2_w, lin2_b, bn7, 512, 256, t2);
  hipLaunchKernelGGL(k_dense, dim3(BB*40),  dim3(256), 0, stream, t2, lin3_w, lin3_b, (const float*)nullptr, 256, 40, (float*)d_out);
}

// Round 12
// 1004.913 us; speedup vs baseline: 1.0227x; 1.0227x over previous
//
#include <hip/hip_runtime.h>
#include <math.h>

#define BB 4
#define NN 2048
#define KK 20
#define EPSF 1e-5f
#define TR 4

__device__ __forceinline__ float leaky(float x){ return x > 0.f ? x : 0.2f*x; }
__device__ __forceinline__ float sigm(float x){ return 1.f/(1.f+expf(-x)); }

// 64-lane max reduce via DPP (row_shr chain + row_bcast), result wave-uniform.
__device__ __forceinline__ unsigned wave_umax_dpp(unsigned x){
  unsigned t;
  t = (unsigned)__builtin_amdgcn_update_dpp(0, (int)x, 0x111, 0xf, 0xf, true); x = x > t ? x : t; // row_shr:1
  t = (unsigned)__builtin_amdgcn_update_dpp(0, (int)x, 0x112, 0xf, 0xf, true); x = x > t ? x : t; // row_shr:2
  t = (unsigned)__builtin_amdgcn_update_dpp(0, (int)x, 0x114, 0xf, 0xf, true); x = x > t ? x : t; // row_shr:4
  t = (unsigned)__builtin_amdgcn_update_dpp(0, (int)x, 0x118, 0xf, 0xf, true); x = x > t ? x : t; // row_shr:8
  t = (unsigned)__builtin_amdgcn_update_dpp(0, (int)x, 0x142, 0xf, 0xf, true); x = x > t ? x : t; // row_bcast:15
  t = (unsigned)__builtin_amdgcn_update_dpp(0, (int)x, 0x143, 0xf, 0xf, true); x = x > t ? x : t; // row_bcast:31
  return (unsigned)__builtin_amdgcn_readlane((int)x, 63);
}

// --- KNN: top-20 of pd[n,m] = 2*dot - xx[n] - xx[m], ties -> smaller index ---
// R4 structure (TR=4 rows/block, 1 row/wave, vectorized dot, DPP extraction),
// with xx computed INLINE (same c-ascending fmaf chain -> bit-identical pd).
__global__ __launch_bounds__(256) void k_knn(const float* __restrict__ X, long bstride, int C,
                      int* __restrict__ idx){
  __shared__ unsigned int pdrow[TR][NN];   // exactly 32 KB
  int rowsPerB = NN/TR;
  int b = blockIdx.x / rowsPerB;
  int r0 = (blockIdx.x % rowsPerB) * TR;
  const float* xb = X + (long)b*bstride;
  int tid = threadIdx.x;
  int m0 = tid << 3;                        // 8 consecutive m per thread

  float acc[4][8];
  float cxx[4] = {0.f,0.f,0.f,0.f};         // xx of the 4 rows
  float vxx[8] = {0.f,0.f,0.f,0.f,0.f,0.f,0.f,0.f}; // xx of the 8 m's
  #pragma unroll
  for (int r = 0; r < 4; ++r)
    #pragma unroll
    for (int j = 0; j < 8; ++j) acc[r][j] = 0.f;
  for (int c = 0; c < C; ++c){
    const float* xcp = xb + (long)c*NN;
    float4 ctr = *(const float4*)(xcp + r0);
    float4 va = *(const float4*)(xcp + m0);
    float4 vb = *(const float4*)(xcp + m0 + 4);
    float v[8] = {va.x,va.y,va.z,va.w,vb.x,vb.y,vb.z,vb.w};
    #pragma unroll
    for (int j = 0; j < 8; ++j){
      acc[0][j] = fmaf(ctr.x, v[j], acc[0][j]);
      acc[1][j] = fmaf(ctr.y, v[j], acc[1][j]);
      acc[2][j] = fmaf(ctr.z, v[j], acc[2][j]);
      acc[3][j] = fmaf(ctr.w, v[j], acc[3][j]);
    }
    cxx[0] = fmaf(ctr.x, ctr.x, cxx[0]);
    cxx[1] = fmaf(ctr.y, ctr.y, cxx[1]);
    cxx[2] = fmaf(ctr.z, ctr.z, cxx[2]);
    cxx[3] = fmaf(ctr.w, ctr.w, cxx[3]);
    #pragma unroll
    for (int j = 0; j < 8; ++j) vxx[j] = fmaf(v[j], v[j], vxx[j]);
  }
  #pragma unroll
  for (int r = 0; r < 4; ++r){
    unsigned u[8];
    #pragma unroll
    for (int j = 0; j < 8; ++j){
      float pd = 2.f*acc[r][j] - cxx[r] - vxx[j];
      unsigned uu = __float_as_uint(pd);
      uu ^= (uu & 0x80000000u) ? 0xFFFFFFFFu : 0x80000000u;  // order-preserving
      u[j] = uu;
    }
    *(uint4*)&pdrow[r][m0]     = make_uint4(u[0],u[1],u[2],u[3]);
    *(uint4*)&pdrow[r][m0 + 4] = make_uint4(u[4],u[5],u[6],u[7]);
  }
  __syncthreads();

  int wave = tid >> 6, lane = tid & 63;
  int r = wave;  // one wave per row
  unsigned long long k1 = 0ull, k2 = 0ull;
  #pragma unroll
  for (int j = 0; j < 32; ++j){
    int m = lane + (j<<6);
    unsigned long long key = ((unsigned long long)pdrow[r][m] << 11) | (unsigned)(2047 - m);
    if (key > k1){ k2 = k1; k1 = key; }
    else if (key > k2){ k2 = key; }
  }
  unsigned removed = 0u;
  int* orow = idx + ((long)b*NN + r0 + r)*KK;
  for (int sel = 0; sel < KK; ++sel){
    unsigned p = (unsigned)(k1 >> 11);      // pd32; 0 iff lane exhausted
    unsigned g = wave_umax_dpp(p);
    unsigned long long tied = __ballot(p == g);
    if (__builtin_popcountll(tied) > 1){
      // rare: exact pd-bit tie across lanes -> pick smallest m (max of 2047-m)
      unsigned low = (p == g) ? (unsigned)(k1 & 2047ull) : 0u;
      unsigned gl = wave_umax_dpp(low);
      tied = __ballot((p == g) && (low == gl));
    }
    int owner = (int)__builtin_ctzll(tied);
    if (lane == owner){
      int gm = 2047 - (int)(k1 & 2047ull);
      orow[sel] = gm;
      removed |= 1u << (gm >> 6);
      k1 = k2; k2 = 0ull;
      if (k1 == 0ull && sel < KK-1){
        // lane exhausted its top-2: rescan remaining candidates from LDS
        #pragma unroll
        for (int j = 0; j < 32; ++j){
          if (removed & (1u << j)) continue;
          int m = lane + (j<<6);
          unsigned long long key = ((unsigned long long)pdrow[r][m] << 11) | (unsigned)(2047 - m);
          if (key > k1){ k2 = k1; k1 = key; }
          else if (key > k2){ k2 = key; }
        }
      }
    }
  }
}

// --- naive projections (used only for block 0, C=3) ---
__global__ void k_proj(const float* __restrict__ X, long bstride, int C, int Cout,
                       const float* __restrict__ W, const float* __restrict__ bn,
                       float* __restrict__ Pg, float* __restrict__ PgT,
                       float* __restrict__ Pc, float* __restrict__ PcT){
  int nb = NN/256;
  int t = blockIdx.x;
  int nchunk = t % nb; t /= nb;
  int o = t % Cout; int b = t / Cout;
  int m = nchunk*256 + threadIdx.x;
  const float* xb = X + (long)b*bstride;
  float a1 = 0.f, a2 = 0.f;
  for (int c = 0; c < C; ++c){
    float v  = xb[c*NN + m];
    float wl = W[o*2*C + c], wr = W[o*2*C + C + c];
    a1 += wl*v; a2 += (wr - wl)*v;
  }
  float gg = bn[o], bb = bn[Cout+o], mn = bn[2*Cout+o], vv = bn[3*Cout+o];
  float scale = gg * rsqrtf(vv + EPSF);
  float bias  = bb - mn*scale;
  float pg = scale*a1;
  float pc = scale*a2 + bias;
  Pg [((long)b*Cout + o)*NN + m] = pg;
  PgT[((long)b*NN + m)*Cout + o] = pg;
  Pc [((long)b*Cout + o)*NN + m] = pc;
  PcT[((long)b*NN + m)*Cout + o] = pc;
}

// --- tiled projections: 64(o) x 128(n) per block, c-chunks of 32 in LDS ---
__global__ __launch_bounds__(256) void k_proj_t(const float* __restrict__ X, long bstride, int C, int Cout,
                         const float* __restrict__ W, const float* __restrict__ bn,
                         float* __restrict__ Pg, float* __restrict__ PgT,
                         float* __restrict__ Pc, float* __restrict__ PcT){
  __shared__ float xs[32][128];    // 16 KB  X chunk
  __shared__ float wls[64][33];    // 8.4 KB W_left chunk (pad 33)
  __shared__ float wds[64][33];    // 8.4 KB (W_right - W_left) chunk
  int t = blockIdx.x;
  int nb = t & 15; t >>= 4;        // NN/128 = 16 n-tiles
  int nob = Cout >> 6;
  int ob = t % nob; int b = t / nob;
  int n0 = nb << 7, o0 = ob << 6;
  int tid = threadIdx.x;
  int tx = tid & 15, ty = tid >> 4;   // tx: 16 n-slots (x4), ty: 16 o-quads
  const float* xb = X + (long)b*bstride + n0;

  float ag[4][8], ac[4][8];
  #pragma unroll
  for (int i = 0; i < 4; ++i)
    #pragma unroll
    for (int j = 0; j < 8; ++j){ ag[i][j] = 0.f; ac[i][j] = 0.f; }

  for (int cc = 0; cc < C; cc += 32){
    {
      int col4 = tid & 31;   // col = col4*4
      int ci0 = tid >> 5;    // 0..7
      #pragma unroll
      for (int q = 0; q < 4; ++q){
        int ci = ci0 + (q << 3);
        float4 v = *(const float4*)(xb + (long)(cc + ci)*NN + (col4 << 2));
        *(float4*)&xs[ci][col4 << 2] = v;
      }
    }
    {
      int ci4 = tid & 7;     // c = ci4*4
      int oi0 = tid >> 3;    // 0..31
      #pragma unroll
      for (int q = 0; q < 2; ++q){
        int oi = oi0 + (q << 5);
        const float* wrow = W + (long)(o0 + oi)*2*C + cc + (ci4 << 2);
        float4 wl = *(const float4*)(wrow);
        float4 wr = *(const float4*)(wrow + C);
        wls[oi][(ci4 << 2) + 0] = wl.x;
        wls[oi][(ci4 << 2) + 1] = wl.y;
        wls[oi][(ci4 << 2) + 2] = wl.z;
        wls[oi][(ci4 << 2) + 3] = wl.w;
        wds[oi][(ci4 << 2) + 0] = wr.x - wl.x;
        wds[oi][(ci4 << 2) + 1] = wr.y - wl.y;
        wds[oi][(ci4 << 2) + 2] = wr.z - wl.z;
        wds[oi][(ci4 << 2) + 3] = wr.w - wl.w;
      }
    }
    __syncthreads();
    #pragma unroll 8
    for (int ci = 0; ci < 32; ++ci){
      float4 xa  = *(const float4*)&xs[ci][tx << 2];
      float4 xc2 = *(const float4*)&xs[ci][64 + (tx << 2)];
      #pragma unroll
      for (int oo = 0; oo < 4; ++oo){
        float wl = wls[(ty << 2) + oo][ci];
        float wd = wds[(ty << 2) + oo][ci];
        ag[oo][0] = fmaf(wl, xa.x, ag[oo][0]); ag[oo][1] = fmaf(wl, xa.y, ag[oo][1]);
        ag[oo][2] = fmaf(wl, xa.z, ag[oo][2]); ag[oo][3] = fmaf(wl, xa.w, ag[oo][3]);
        ag[oo][4] = fmaf(wl, xc2.x, ag[oo][4]); ag[oo][5] = fmaf(wl, xc2.y, ag[oo][5]);
        ag[oo][6] = fmaf(wl, xc2.z, ag[oo][6]); ag[oo][7] = fmaf(wl, xc2.w, ag[oo][7]);
        ac[oo][0] = fmaf(wd, xa.x, ac[oo][0]); ac[oo][1] = fmaf(wd, xa.y, ac[oo][1]);
        ac[oo][2] = fmaf(wd, xa.z, ac[oo][2]); ac[oo][3] = fmaf(wd, xa.w, ac[oo][3]);
        ac[oo][4] = fmaf(wd, xc2.x, ac[oo][4]); ac[oo][5] = fmaf(wd, xc2.y, ac[oo][5]);
        ac[oo][6] = fmaf(wd, xc2.z, ac[oo][6]); ac[oo][7] = fmaf(wd, xc2.w, ac[oo][7]);
      }
    }
    __syncthreads();
  }

  float scl[4], bia[4];
  #pragma unroll
  for (int oo = 0; oo < 4; ++oo){
    int o = o0 + (ty << 2) + oo;
    scl[oo] = bn[o] * rsqrtf(bn[3*Cout + o] + EPSF);
    bia[oo] = bn[Cout + o] - bn[2*Cout + o]*scl[oo];
  }
  #pragma unroll
  for (int oo = 0; oo < 4; ++oo){
    long rb = ((long)b*Cout + o0 + (ty << 2) + oo)*NN + n0;
    float4 g0 = {scl[oo]*ag[oo][0], scl[oo]*ag[oo][1], scl[oo]*ag[oo][2], scl[oo]*ag[oo][3]};
    float4 g1 = {scl[oo]*ag[oo][4], scl[oo]*ag[oo][5], scl[oo]*ag[oo][6], scl[oo]*ag[oo][7]};
    float4 c0 = {fmaf(scl[oo], ac[oo][0], bia[oo]), fmaf(scl[oo], ac[oo][1], bia[oo]),
                 fmaf(scl[oo], ac[oo][2], bia[oo]), fmaf(scl[oo], ac[oo][3], bia[oo])};
    float4 c1 = {fmaf(scl[oo], ac[oo][4], bia[oo]), fmaf(scl[oo], ac[oo][5], bia[oo]),
                 fmaf(scl[oo], ac[oo][6], bia[oo]), fmaf(scl[oo], ac[oo][7], bia[oo])};
    *(float4*)(Pg + rb + (tx << 2))      = g0;
    *(float4*)(Pg + rb + 64 + (tx << 2)) = g1;
    *(float4*)(Pc + rb + (tx << 2))      = c0;
    *(float4*)(Pc + rb + 64 + (tx << 2)) = c1;
  }
  #pragma unroll
  for (int j = 0; j < 8; ++j){
    int n = n0 + ((j < 4) ? (tx << 2) + j : 64 + (tx << 2) + (j - 4));
    long rb = ((long)b*NN + n)*Cout + o0 + (ty << 2);
    float4 tg = {scl[0]*ag[0][j], scl[1]*ag[1][j], scl[2]*ag[2][j], scl[3]*ag[3][j]};
    float4 tc = {fmaf(scl[0], ac[0][j], bia[0]), fmaf(scl[1], ac[1][j], bia[1]),
                 fmaf(scl[2], ac[2][j], bia[2]), fmaf(scl[3], ac[3][j], bia[3])};
    *(float4*)(PgT + rb) = tg;
    *(float4*)(PcT + rb) = tc;
  }
}

// --- channel mean/max over (n,k) of leaky(Pg[idx]+Pc[n]) ---
__global__ void k_cstats(const float* __restrict__ Pg, const float* __restrict__ Pc,
                         const int* __restrict__ idx, int Cout,
                         float* __restrict__ cmean, float* __restrict__ cmax){
  int b = blockIdx.x / Cout, o = blockIdx.x % Cout;
  const float* pg = Pg + ((long)b*Cout + o)*NN;
  const float* pc = Pc + ((long)b*Cout + o)*NN;
  const int* id = idx + (long)b*NN*KK;
  int tid = threadIdx.x;
  float s = 0.f, mx = -INFINITY;
  for (int i = tid; i < NN*KK; i += 256){
    int n = i / KK;
    int iv = id[i];
    float v = leaky(pg[iv] + pc[n]);
    s += v; mx = fmaxf(mx, v);
  }
  __shared__ float ss[256], sm[256];
  ss[tid] = s; sm[tid] = mx; __syncthreads();
  for (int st = 128; st; st >>= 1){
    if (tid < st){ ss[tid] += ss[tid+st]; sm[tid] = fmaxf(sm[tid], sm[tid+st]); }
    __syncthreads();
  }
  if (tid == 0){ cmean[blockIdx.x] = ss[0]/(float)(NN*KK); cmax[blockIdx.x] = sm[0]; }
}

// --- channel attention MLP ---
__global__ void k_catt(const float* __restrict__ cmean, const float* __restrict__ cmax,
                       const float* __restrict__ fc1, const float* __restrict__ fc2,
                       int Cout, int r, float* __restrict__ ca){
  int b = blockIdx.x, tid = threadIdx.x;
  __shared__ float h1m[32], h1x[32];
  __shared__ float mv[256], xv[256];
  if (tid < Cout){ mv[tid] = cmean[b*Cout+tid]; xv[tid] = cmax[b*Cout+tid]; }
  __syncthreads();
  if (tid < r){
    float am = 0.f, ax = 0.f;
    for (int c = 0; c < Cout; ++c){ float w = fc1[tid*Cout+c]; am += w*mv[c]; ax += w*xv[c]; }
    h1m[tid] = fmaxf(am, 0.f); h1x[tid] = fmaxf(ax, 0.f);
  }
  __syncthreads();
  if (tid < Cout){
    float a = 0.f;
    for (int j = 0; j < r; ++j) a += fc2[tid*r+j]*(h1m[j] + h1x[j]);
    ca[b*Cout+tid] = sigm(a);
  }
}

// --- spatial mean/max over channels of act*ca (float4 rows of PgT/PcT) ---
__global__ void k_sstats(const float* __restrict__ PgT, const float* __restrict__ PcT,
                         const int* __restrict__ idx, const float* __restrict__ ca,
                         int Cout, float* __restrict__ s){
  long i = (long)blockIdx.x*256 + threadIdx.x; // over BB*NN*KK
  int kk = (int)(i % KK); long t = i / KK; int n = (int)(t % NN); int b = (int)(t / NN);
  int iv = idx[((long)b*NN + n)*KK + kk];
  const float4* pg4 = (const float4*)(PgT + ((long)b*NN + iv)*Cout);
  const float4* pc4 = (const float4*)(PcT + ((long)b*NN + n)*Cout);
  const float4* ca4 = (const float4*)(ca + b*Cout);
  float sum = 0.f, mx = -INFINITY;
  int q = Cout >> 2;
  for (int o = 0; o < q; ++o){
    float4 a = pg4[o], c = pc4[o], w = ca4[o];
    float v0 = leaky(a.x + c.x) * w.x;
    float v1 = leaky(a.y + c.y) * w.y;
    float v2 = leaky(a.z + c.z) * w.z;
    float v3 = leaky(a.w + c.w) * w.w;
    sum += v0; mx = fmaxf(mx, v0);
    sum += v1; mx = fmaxf(mx, v1);
    sum += v2; mx = fmaxf(mx, v2);
    sum += v3; mx = fmaxf(mx, v3);
  }
  s[((long)b*2*NN + n)*KK + kk]      = sum/(float)Cout;
  s[((long)b*2*NN + NN + n)*KK + kk] = mx;
}

// --- 5x5 spatial conv (pad 2) + sigmoid ---
__global__ void k_sconv(const float* __restrict__ s, const float* __restrict__ sw,
                        float* __restrict__ sa){
  long i = (long)blockIdx.x*256 + threadIdx.x; // over BB*NN*KK
  int kk = (int)(i % KK); long t = i / KK; int n = (int)(t % NN); int b = (int)(t / NN);
  float acc = 0.f;
  for (int ci = 0; ci < 2; ++ci)
    for (int dy = 0; dy < 5; ++dy){
      int nn = n + dy - 2; if (nn < 0 || nn >= NN) continue;
      for (int dx = 0; dx < 5; ++dx){
        int kx = kk + dx - 2; if (kx < 0 || kx >= KK) continue;
        acc += sw[ci*25 + dy*5 + dx] * s[((long)b*2*NN + ci*NN + nn)*KK + kx];
      }
    }
  sa[i] = sigm(acc);
}

// --- final: max over k of act*ca*sa -> xc ---
__global__ void k_final(const float* __restrict__ Pg, const float* __restrict__ Pc,
                        const int* __restrict__ idx, const float* __restrict__ ca,
                        const float* __restrict__ sa, int Cout, int outoff,
                        float* __restrict__ xc){
  long i = (long)blockIdx.x*256 + threadIdx.x; // over BB*Cout*NN, n fastest
  int n = (int)(i % NN); long t = i / NN; int o = (int)(t % Cout); int b = (int)(t / Cout);
  const float* pg = Pg + ((long)b*Cout + o)*NN;
  float pcv = Pc[((long)b*Cout + o)*NN + n];
  float cav = ca[b*Cout + o];
  const int* id   = idx + ((long)b*NN + n)*KK;
  const float* sb = sa  + ((long)b*NN + n)*KK;
  float mx = -INFINITY;
  for (int kk = 0; kk < KK; ++kk){
    float v = leaky(pg[id[kk]] + pcv) * cav * sb[kk];
    mx = fmaxf(mx, v);
  }
  xc[((long)b*512 + outoff + o)*NN + n] = mx;
}

// --- gemm5 tiled: 64(o) x 128(n) per block, fused bn5+leaky+partial pool ---
__global__ __launch_bounds__(256) void k_gemm5(const float* __restrict__ xc, const float* __restrict__ W5,
                        const float* __restrict__ bn5, float* __restrict__ gpart){
  __shared__ float xs[32][128];    // 16 KB
  __shared__ float wsd[64][33];    // 8.4 KB, pad 33 -> conflict-free ty reads
  int t = blockIdx.x;
  int nb = t & 15; t >>= 4;
  int ob = t & 15; int b = t >> 4;
  int n0 = nb << 7, o0 = ob << 6;
  int tid = threadIdx.x;
  int tx = tid & 15, ty = tid >> 4;   // ty: 16 o-quads, tx: 16 n-slots
  const float* xb = xc + (long)b*512*NN + n0;

  float acc[4][8];
  #pragma unroll
  for (int i = 0; i < 4; ++i)
    #pragma unroll
    for (int j = 0; j < 8; ++j) acc[i][j] = 0.f;

  for (int cc = 0; cc < 16; ++cc){
    {
      int col4 = tid & 31;   // col = col4*4
      int ci0 = tid >> 5;    // 0..7
      #pragma unroll
      for (int q = 0; q < 4; ++q){
        int ci = ci0 + (q << 3);
        float4 v = *(const float4*)(xb + (long)(cc*32 + ci)*NN + (col4 << 2));
        *(float4*)&xs[ci][col4 << 2] = v;
      }
    }
    {
      int ci4 = tid & 7;
      int oi0 = tid >> 3;    // 0..31
      #pragma unroll
      for (int q = 0; q < 2; ++q){
        int oi = oi0 + (q << 5);
        float4 w = *(const float4*)(W5 + (long)(o0 + oi)*512 + cc*32 + (ci4 << 2));
        wsd[oi][(ci4 << 2) + 0] = w.x;
        wsd[oi][(ci4 << 2) + 1] = w.y;
        wsd[oi][(ci4 << 2) + 2] = w.z;
        wsd[oi][(ci4 << 2) + 3] = w.w;
      }
    }
    __syncthreads();
    #pragma unroll 8
    for (int ci = 0; ci < 32; ++ci){
      float4 xa = *(const float4*)&xs[ci][tx << 2];
      float4 xc2 = *(const float4*)&xs[ci][64 + (tx << 2)];
      float w0 = wsd[(ty << 2) + 0][ci];
      float w1 = wsd[(ty << 2) + 1][ci];
      float w2 = wsd[(ty << 2) + 2][ci];
      float w3 = wsd[(ty << 2) + 3][ci];
      acc[0][0] = fmaf(w0, xa.x, acc[0][0]); acc[0][1] = fmaf(w0, xa.y, acc[0][1]);
      acc[0][2] = fmaf(w0, xa.z, acc[0][2]); acc[0][3] = fmaf(w0, xa.w, acc[0][3]);
      acc[0][4] = fmaf(w0, xc2.x, acc[0][4]); acc[0][5] = fmaf(w0, xc2.y, acc[0][5]);
      acc[0][6] = fmaf(w0, xc2.z, acc[0][6]); acc[0][7] = fmaf(w0, xc2.w, acc[0][7]);
      acc[1][0] = fmaf(w1, xa.x, acc[1][0]); acc[1][1] = fmaf(w1, xa.y, acc[1][1]);
      acc[1][2] = fmaf(w1, xa.z, acc[1][2]); acc[1][3] = fmaf(w1, xa.w, acc[1][3]);
      acc[1][4] = fmaf(w1, xc2.x, acc[1][4]); acc[1][5] = fmaf(w1, xc2.y, acc[1][5]);
      acc[1][6] = fmaf(w1, xc2.z, acc[1][6]); acc[1][7] = fmaf(w1, xc2.w, acc[1][7]);
      acc[2][0] = fmaf(w2, xa.x, acc[2][0]); acc[2][1] = fmaf(w2, xa.y, acc[2][1]);
      acc[2][2] = fmaf(w2, xa.z, acc[2][2]); acc[2][3] = fmaf(w2, xa.w, acc[2][3]);
      acc[2][4] = fmaf(w2, xc2.x, acc[2][4]); acc[2][5] = fmaf(w2, xc2.y, acc[2][5]);
      acc[2][6] = fmaf(w2, xc2.z, acc[2][6]); acc[2][7] = fmaf(w2, xc2.w, acc[2][7]);
      acc[3][0] = fmaf(w3, xa.x, acc[3][0]); acc[3][1] = fmaf(w3, xa.y, acc[3][1]);
      acc[3][2] = fmaf(w3, xa.z, acc[3][2]); acc[3][3] = fmaf(w3, xa.w, acc[3][3]);
      acc[3][4] = fmaf(w3, xc2.x, acc[3][4]); acc[3][5] = fmaf(w3, xc2.y, acc[3][5]);
      acc[3][6] = fmaf(w3, xc2.z, acc[3][6]); acc[3][7] = fmaf(w3, xc2.w, acc[3][7]);
    }
    __syncthreads();
  }

  // bn5 + leaky + pool over this thread's 8 n
  float psum[4], pmax[4];
  #pragma unroll
  for (int oo = 0; oo < 4; ++oo){
    int o = o0 + (ty << 2) + oo;
    float scale = bn5[o] * rsqrtf(bn5[3072 + o] + EPSF);
    float bias  = bn5[1024 + o] - bn5[2048 + o] * scale;
    float s = 0.f, mx = -INFINITY;
    #pragma unroll
    for (int j = 0; j < 8; ++j){
      float v = leaky(fmaf(scale, acc[oo][j], bias));
      s += v; mx = fmaxf(mx, v);
    }
    psum[oo] = s; pmax[oo] = mx;
  }
  __syncthreads();
  float* ps = &xs[0][0];          // [64][17]
  float* pm = ps + 64*17;         // [64][17]  (2176 floats < 4096)
  #pragma unroll
  for (int oo = 0; oo < 4; ++oo){
    int o = (ty << 2) + oo;
    ps[o*17 + tx] = psum[oo];
    pm[o*17 + tx] = pmax[oo];
  }
  __syncthreads();
  if (tid < 64){
    float s = 0.f, mx = -INFINITY;
    #pragma unroll
    for (int j = 0; j < 16; ++j){
      s += ps[tid*17 + j];
      mx = fmaxf(mx, pm[tid*17 + j]);
    }
    long base = ((long)(b*16 + nb))*1024 + o0 + tid;
    gpart[base] = s;
    gpart[65536 + base] = mx;
  }
}

// --- finish pool: g = [max, sum/2048] ---
__global__ void k_pool2(const float* __restrict__ gpart, float* __restrict__ g){
  int i = blockIdx.x*256 + threadIdx.x;  // over 4096
  int b = i >> 10, o = i & 1023;
  float s = 0.f, mx = -INFINITY;
  for (int nb = 0; nb < 16; ++nb){
    s += gpart[((long)(b*16 + nb))*1024 + o];
    mx = fmaxf(mx, gpart[65536 + ((long)(b*16 + nb))*1024 + o]);
  }
  g[b*2048 + o] = mx;
  g[b*2048 + 1024 + o] = s * (1.f/2048.f);
}

// --- dense: out = [leaky(bn(.))] (w @ in [+ bias]) ---
__global__ void k_dense(const float* __restrict__ in, const float* __restrict__ w,
                        const float* __restrict__ bias, const float* __restrict__ bnp,
                        int Cin, int Cout, float* __restrict__ out){
  int b = blockIdx.x / Cout, j = blockIdx.x % Cout;
  int tid = threadIdx.x;
  float a = 0.f;
  for (int c = tid; c < Cin; c += 256) a += w[(long)j*Cin + c]*in[(long)b*Cin + c];
  __shared__ float ss[256];
  ss[tid] = a; __syncthreads();
  for (int st = 128; st; st >>= 1){
    if (tid < st) ss[tid] += ss[tid+st];
    __syncthreads();
  }
  if (tid == 0){
    float v = ss[0];
    if (bias) v += bias[j];
    if (bnp){
      float scale = bnp[j]*rsqrtf(bnp[3*Cout+j] + EPSF);
      float bb    = bnp[Cout+j] - bnp[2*Cout+j]*scale;
      v = leaky(v*scale + bb);
    }
    out[b*Cout + j] = v;
  }
}

extern "C" void kernel_launch(void* const* d_in, const int* in_sizes, int n_in,
                              void* d_out, int out_size, void* d_ws, size_t ws_size,
                              hipStream_t stream){
  (void)in_sizes; (void)n_in; (void)out_size;
  const float* x  = (const float*)d_in[0];
  const float* Wb[4]  = {(const float*)d_in[1], (const float*)d_in[2], (const float*)d_in[3], (const float*)d_in[4]};
  const float* W5     = (const float*)d_in[5];
  const float* bnb[4] = {(const float*)d_in[6], (const float*)d_in[7], (const float*)d_in[8], (const float*)d_in[9]};
  const float* bn5    = (const float*)d_in[10];
  const float* bn6    = (const float*)d_in[11];
  const float* bn7    = (const float*)d_in[12];
  const float* fc1b[4] = {(const float*)d_in[13], (const float*)d_in[16], (const float*)d_in[19], (const float*)d_in[22]};
  const float* fc2b[4] = {(const float*)d_in[14], (const float*)d_in[17], (const float*)d_in[20], (const float*)d_in[23]};
  const float* swb[4]  = {(const float*)d_in[15], (const float*)d_in[18], (const float*)d_in[21], (const float*)d_in[24]};
  const float* lin1_w = (const float*)d_in[25];
  const float* lin2_w = (const float*)d_in[26];
  const float* lin2_b = (const float*)d_in[27];
  const float* lin3_w = (const float*)d_in[28];
  const float* lin3_b = (const float*)d_in[29];

  // workspace layout (floats)
  float* ws = (float*)d_ws;
  float* xc = ws;                                  // 4*512*2048 = 4,194,304
  float* tb = ws + (size_t)BB*512*NN;
  // (first 8192 floats of tb reserved — layout kept identical to prior rounds)
  int*   idx  = (int*)(tb + 8192);                 // 163,840 ints
  float* Pg   = tb + 8192 + 163840;                // 2,097,152 each (max Cout=256)
  float* PgT  = Pg  + 2097152;
  float* Pc   = PgT + 2097152;
  float* PcT  = Pc  + 2097152;
  float* cmean = PcT + 2097152;                    // 1024
  float* cmax  = cmean + 1024;
  float* ca    = cmax + 1024;
  float* s     = ca + 1024;                        // 327,680
  float* sa    = s + 327680;                       // 163,840
  // post-block region (reuses tb)
  float* gpart = tb;                               // 131,072 (sums + maxes)
  float* g  = tb + 131072;                         // 8,192
  float* t1 = g + 8192;                            // 2,048
  float* t2 = t1 + 2048;                           // 1,024
  size_t needed = ((size_t)BB*512*NN + 9055232) * 4;
  if (ws_size < needed) return;  // workspace too small: fail visibly

  const int Cin [4] = {3, 64, 64, 128};
  const int Cout[4] = {64, 64, 128, 256};
  const int inoff[4]  = {0, 0, 64, 128};
  const int outoff[4] = {0, 64, 128, 256};

  for (int blk = 0; blk < 4; ++blk){
    const float* Xp; long bstr;
    if (blk == 0){ Xp = x; bstr = 3l*NN; }
    else { Xp = xc + (long)inoff[blk]*NN; bstr = 512l*NN; }
    int C = Cin[blk], Co = Cout[blk];
    hipLaunchKernelGGL(k_knn,   dim3(BB*NN/TR),  dim3(256), 0, stream, Xp, bstr, C, idx);
    if (blk == 0){
      hipLaunchKernelGGL(k_proj,  dim3(BB*Co*(NN/256)), dim3(256), 0, stream, Xp, bstr, C, Co, Wb[blk], bnb[blk], Pg, PgT, Pc, PcT);
    } else {
      hipLaunchKernelGGL(k_proj_t, dim3(BB*(Co>>6)*16), dim3(256), 0, stream, Xp, bstr, C, Co, Wb[blk], bnb[blk], Pg, PgT, Pc, PcT);
    }
    hipLaunchKernelGGL(k_cstats, dim3(BB*Co), dim3(256), 0, stream, Pg, Pc, idx, Co, cmean, cmax);
    hipLaunchKernelGGL(k_catt,  dim3(BB), dim3(256), 0, stream, cmean, cmax, fc1b[blk], fc2b[blk], Co, Co/8, ca);
    hipLaunchKernelGGL(k_sstats, dim3(BB*NN*KK/256), dim3(256), 0, stream, PgT, PcT, idx, ca, Co, s);
    hipLaunchKernelGGL(k_sconv, dim3(BB*NN*KK/256), dim3(256), 0, stream, s, swb[blk], sa);
    hipLaunchKernelGGL(k_final, dim3(BB*Co*NN/256), dim3(256), 0, stream, Pg, Pc, idx, ca, sa, Co, outoff[blk], xc);
  }
  hipLaunchKernelGGL(k_gemm5, dim3(BB*16*16), dim3(256), 0, stream, xc, W5, bn5, gpart);
  hipLaunchKernelGGL(k_pool2, dim3(16), dim3(256), 0, stream, gpart, g);
  hipLaunchKernelGGL(k_dense, dim3(BB*512), dim3(256), 0, stream, g,  lin1_w, (const float*)nullptr, bn6, 2048, 512, t1);
  hipLaunchKernelGGL(k_dense, dim3(BB*256), dim3(256), 0, stream, t1, lin2_w, lin2_b, bn7, 512, 256, t2);
  hipLaunchKernelGGL(k_dense, dim3(BB*40),  dim3(256), 0, stream, t2, lin3_w, lin3_b, (const float*)nullptr, 256, 40, (float*)d_out);
}